// Round 3
// baseline (426.820 us; speedup 1.0000x reference)
//
#include <hip/hip_runtime.h>

// Problem: B=8, C=256, H=W=160. n = B*C = 2048 planes.
// Per plane: l[h]=x[h,:]·fcw_w ; alpha=softmax_h(l) ; row[w]=sum_h alpha[h]x[h,w]
//            beta=softmax_w(row*sum(fch_w)) ; s=sum_w beta[w]row[w] ; out[:,:]=s
// Biases are softmax-shift-invariant -> ignored.
//
// One block per plane. 320 threads = (q in [0,40), v in [0,8)).
// Thread owns float4 column block w in [4q,4q+4), rows h in [20v, 20v+20).
//
// v3: ONLINE softmax over row chunks. x is read exactly once (v1's virtue)
// but only CHUNK=5 float4 are live at a time (~50 VGPR, v2's virtue).
// Per chunk: load 5 rows -> dot partials -> LDS reduce -> l[h] -> running
// (m, Z, rowacc) update with rescale (flash-attention style). The 8 v-groups'
// partial softmaxes merge at the end: m=max m_v, row=sum e^{m_v-m} rowacc_v / Z.
// Plain float4 stores (v2's nontemporal stores inflated WRITE_SIZE 1.4x).

#define HH 160
#define WW 160
#define NPLANE (HH * WW)
#define BLOCK 320
#define RPT 20    // rows per v-group
#define QN 40     // float4 columns per row
#define CHUNK 5   // rows per group per chunk
#define NCHUNK 4  // RPT / CHUNK
#define PSTR 41   // pad 41: bank = (9h+q)%32 -> near-conflict-free gather by h

__global__ void __launch_bounds__(BLOCK, 8) sa1_kernel(
    const float* __restrict__ x,
    const float* __restrict__ fcw_w,
    const float* __restrict__ fch_w,
    float* __restrict__ out)
{
    const int n = blockIdx.x;
    const int t = threadIdx.x;
    const int q = t % QN;
    const int v = t / QN;

    __shared__ float pbuf[HH * PSTR];  // dot partials; later row partials [8][160]
    __shared__ float larr[HH];         // l[h]; later row[]
    __shared__ float gm[8], gz[8];     // per-group running max / Z
    __shared__ float sc[4];            // [2]=S(=sum fch_w), [3]=s

    const float* xp = x + (size_t)n * NPLANE;
    float*       op = out + (size_t)n * NPLANE;

    const float4 ww = *(const float4*)(fcw_w + 4 * q);

    // ---- S = sum(fch_w) on wave1 lanes 0..31, overlapped with chunk 0 ----
    if (t >= 64 && t < 96) {
        const int u = t - 64;
        float s = 0.f;
#pragma unroll
        for (int j = 0; j < 5; ++j) s += fch_w[u + 32 * j];
#pragma unroll
        for (int off = 16; off >= 1; off >>= 1)
            s += __shfl_down(s, off, 32);
        if (u == 0) sc[2] = s;
    }

    // ---- online softmax over 4 chunks of 5 rows per group ----
    float  m_run = -3.0e38f;
    float  Z_run = 0.f;
    float4 acc   = make_float4(0.f, 0.f, 0.f, 0.f);

    for (int c = 0; c < NCHUNK; ++c) {
        // load my 5 float4 (coalesced) + dot partials into LDS
        float4 x4[CHUNK];
#pragma unroll
        for (int r = 0; r < CHUNK; ++r) {
            const int h = v * RPT + c * CHUNK + r;
            x4[r] = *(const float4*)(xp + (size_t)h * WW + 4 * q);
            pbuf[h * PSTR + q] =
                x4[r].x * ww.x + x4[r].y * ww.y + x4[r].z * ww.z + x4[r].w * ww.w;
        }
        __syncthreads();

        // l[h] for this chunk's 40 rows: wave c, lanes 0..39 (rotates per chunk)
        const int tt = t - 64 * c;
        if (tt >= 0 && tt < QN) {
            const int h = RPT * (tt / CHUNK) + c * CHUNK + (tt % CHUNK);
            const float* pr = pbuf + h * PSTR;
            float s0 = 0.f, s1 = 0.f, s2 = 0.f, s3 = 0.f;
#pragma unroll
            for (int qq = 0; qq < QN; qq += 4) {
                s0 += pr[qq]; s1 += pr[qq + 1]; s2 += pr[qq + 2]; s3 += pr[qq + 3];
            }
            larr[h] = (s0 + s1) + (s2 + s3);
        }
        __syncthreads();

        // running update (x4 still in registers; larr reads are broadcasts)
        float lv[CHUNK];
        float mc = -3.0e38f;
#pragma unroll
        for (int r = 0; r < CHUNK; ++r) {
            lv[r] = larr[v * RPT + c * CHUNK + r];
            mc = fmaxf(mc, lv[r]);
        }
        const float m_new = fmaxf(m_run, mc);
        const float scale = __expf(m_run - m_new);  // first chunk: exp(-inf)=0
        Z_run *= scale;
        acc.x *= scale; acc.y *= scale; acc.z *= scale; acc.w *= scale;
#pragma unroll
        for (int r = 0; r < CHUNK; ++r) {
            const float a = __expf(lv[r] - m_new);
            Z_run += a;
            acc.x += a * x4[r].x; acc.y += a * x4[r].y;
            acc.z += a * x4[r].z; acc.w += a * x4[r].w;
        }
        m_run = m_new;
        // no barrier needed here: next chunk touches disjoint pbuf/larr rows,
        // and its own barrier orders the new writes before their reads
    }

    // ---- merge the 8 group-partials ----
    if (q == 0) { gm[v] = m_run; gz[v] = Z_run; }
    __syncthreads();

    float m_g = gm[0];
#pragma unroll
    for (int j = 1; j < 8; ++j) m_g = fmaxf(m_g, gm[j]);
    const float f = __expf(m_run - m_g);  // == exp(gm[v]-m_g), uniform in group
    pbuf[v * WW + 4 * q + 0] = f * acc.x;
    pbuf[v * WW + 4 * q + 1] = f * acc.y;
    pbuf[v * WW + 4 * q + 2] = f * acc.z;
    pbuf[v * WW + 4 * q + 3] = f * acc.w;
    __syncthreads();

    // ---- row[w] = (sum_v part(v,w)) / Z_global   (reuse larr as row[]) ----
    if (t < WW) {
        float rs = 0.f;
#pragma unroll
        for (int vv = 0; vv < 8; ++vv) rs += pbuf[vv * WW + t];
        float zg = 0.f;
#pragma unroll
        for (int j = 0; j < 8; ++j) zg += __expf(gm[j] - m_g) * gz[j];
        larr[t] = rs / zg;
    }
    __syncthreads();

    // ---- wave0: beta softmax + s = sum beta*row ----
    if (t < 32) {
        const float S = sc[2];
        float rv[5], bl[5];
#pragma unroll
        for (int j = 0; j < 5; ++j) { rv[j] = larr[t + 32 * j]; bl[j] = rv[j] * S; }
        float mb = bl[0];
#pragma unroll
        for (int j = 1; j < 5; ++j) mb = fmaxf(mb, bl[j]);
#pragma unroll
        for (int off = 16; off >= 1; off >>= 1)
            mb = fmaxf(mb, __shfl_down(mb, off, 32));
        mb = __shfl(mb, 0, 32);
        float zb = 0.f, sd = 0.f;
#pragma unroll
        for (int j = 0; j < 5; ++j) {
            float e = __expf(bl[j] - mb);
            zb += e; sd += e * rv[j];
        }
#pragma unroll
        for (int off = 16; off >= 1; off >>= 1) {
            zb += __shfl_down(zb, off, 32);
            sd += __shfl_down(sd, off, 32);
        }
        if (t == 0) sc[3] = sd / zb;
    }
    __syncthreads();

    // ---- broadcast store (coalesced float4, plain: nt inflated WRITE_SIZE) ----
    const float sv = sc[3];
    const float4 o = make_float4(sv, sv, sv, sv);
#pragma unroll
    for (int r = 0; r < RPT; ++r)
        *(float4*)(op + (size_t)(v * RPT + r) * WW + 4 * q) = o;
}

extern "C" void kernel_launch(void* const* d_in, const int* in_sizes, int n_in,
                              void* d_out, int out_size, void* d_ws, size_t ws_size,
                              hipStream_t stream) {
    const float* x     = (const float*)d_in[0];
    const float* fcw_w = (const float*)d_in[1];
    // d_in[2] = fcw_b: softmax-shift-invariant, unused
    const float* fch_w = (const float*)d_in[3];
    // d_in[4] = fch_b: softmax-shift-invariant, unused
    float* out = (float*)d_out;

    const int nplanes = 8 * 256;  // B*C
    sa1_kernel<<<nplanes, BLOCK, 0, stream>>>(x, fcw_w, fch_w, out);
}

// Round 4
// 347.309 us; speedup vs baseline: 1.2289x; 1.2289x over previous
//
#include <hip/hip_runtime.h>

// Problem: B=8, C=256, H=W=160. n = B*C = 2048 planes.
// Per plane: l[h]=x[h,:]·fcw_w ; alpha=softmax_h(l) ; row[w]=sum_h alpha[h]x[h,w]
//            beta=softmax_w(row*sum(fch_w)) ; s=sum_w beta[w]row[w] ; out[:,:]=s
// Biases are softmax-shift-invariant -> ignored.
//
// One block per plane. 320 threads = (q in [0,40), v in [0,8)).
// Thread owns float4 column block w in [4q,4q+4), rows h in [20v, 20v+20):
// 20 float4 in registers -> x read from HBM exactly once, fully coalesced.
//
// v4 = v0 (the fastest structure: kernel ~101us, measured 6.26 TB/s effective
// = HBM ceiling for 632 MB of traffic) + NONTEMPORAL x loads and out stores.
// Rationale: WRITE_SIZE was 2.05x the output (v3) with plain stores but
// 1.39x with nt stores (v2) -> the extra HBM writes are dirty-poison
// writebacks from the preceding 800 MiB fill, evicted by our cache
// allocations. x is read once and out is never re-read, so neither stream
// benefits from caching: nt on both minimizes poison eviction -> less
// concurrent writeback BW -> faster at the same structure.
// (occupancy experiments v2/v3 proved occupancy is NOT the bottleneck;
// 3 blocks/CU already saturates BW.)

#define HH 160
#define WW 160
#define NPLANE (HH * WW)
#define BLOCK 320
#define RPT 20   // rows per v-group
#define QN 40    // float4 columns per row
#define PSTR 41  // pad 41: bank = (9h+q)%32 -> conflict-free gather by h

typedef float f32x4 __attribute__((ext_vector_type(4)));

__global__ void __launch_bounds__(BLOCK) sa1_kernel(
    const float* __restrict__ x,
    const float* __restrict__ fcw_w,
    const float* __restrict__ fch_w,
    float* __restrict__ out)
{
    const int n = blockIdx.x;
    const int t = threadIdx.x;
    const int q = t % QN;
    const int v = t / QN;

    __shared__ float pbuf[HH * PSTR];  // logit partials, later row partials [8][160]
    __shared__ float larr[HH];         // logits -> a[h]=exp(l-m) -> row[]
    __shared__ float sc[4];            // m, Z, S(=sum fch_w), s

    const float* xp = x + (size_t)n * NPLANE;
    float*       op = out + (size_t)n * NPLANE;

    const float4 ww = *(const float4*)(fcw_w + 4 * q);

    // ---- load my 20 float4 (coalesced, nontemporal: x is read exactly once) ----
    f32x4 xr[RPT];
#pragma unroll
    for (int r = 0; r < RPT; ++r)
        xr[r] = __builtin_nontemporal_load(
            (const f32x4*)(xp + (size_t)(v * RPT + r) * WW + 4 * q));

    // ---- logit partials: p(h,q) = x4 . ww4 ----
#pragma unroll
    for (int r = 0; r < RPT; ++r) {
        float p = xr[r].x * ww.x + xr[r].y * ww.y + xr[r].z * ww.z + xr[r].w * ww.w;
        pbuf[(v * RPT + r) * PSTR + q] = p;
    }
    __syncthreads();

    // ---- l[h] = sum_q p(h,q)  (threads 0..159, banks (9t+q)%32: 2-way, free) ----
    if (t < HH) {
        const float* pr = pbuf + t * PSTR;
        float s0 = 0.f, s1 = 0.f, s2 = 0.f, s3 = 0.f;
#pragma unroll
        for (int qq = 0; qq < QN; qq += 4) {
            s0 += pr[qq]; s1 += pr[qq + 1]; s2 += pr[qq + 2]; s3 += pr[qq + 3];
        }
        larr[t] = (s0 + s1) + (s2 + s3);
    }
    __syncthreads();

    // ---- wave0: softmax stats m, Z over l[0..159]; wave1: S = sum(fch_w) ----
    if (t < 32) {
        float lv[5];
#pragma unroll
        for (int j = 0; j < 5; ++j) lv[j] = larr[t + 32 * j];
        float m = lv[0];
#pragma unroll
        for (int j = 1; j < 5; ++j) m = fmaxf(m, lv[j]);
#pragma unroll
        for (int off = 16; off >= 1; off >>= 1)
            m = fmaxf(m, __shfl_down(m, off, 32));
        m = __shfl(m, 0, 32);
        float z = 0.f;
#pragma unroll
        for (int j = 0; j < 5; ++j) z += __expf(lv[j] - m);
#pragma unroll
        for (int off = 16; off >= 1; off >>= 1)
            z += __shfl_down(z, off, 32);
        if (t == 0) { sc[0] = m; sc[1] = z; }
    } else if (t >= 64 && t < 96) {
        const int u = t - 64;
        float s = 0.f;
#pragma unroll
        for (int j = 0; j < 5; ++j) s += fch_w[u + 32 * j];
#pragma unroll
        for (int off = 16; off >= 1; off >>= 1)
            s += __shfl_down(s, off, 32);
        if (u == 0) sc[2] = s;
    }
    __syncthreads();

    // ---- a[h] = exp(l[h]-m), once per block (160 expf instead of 6400) ----
    if (t < HH) larr[t] = __expf(larr[t] - sc[0]);
    __syncthreads();

    // ---- row partials: rp = sum_r a[h] * x4  (x4 still in registers) ----
    float4 rp = make_float4(0.f, 0.f, 0.f, 0.f);
#pragma unroll
    for (int r = 0; r < RPT; ++r) {
        const float a = larr[v * RPT + r];  // LDS broadcast read
        rp.x += a * xr[r].x; rp.y += a * xr[r].y;
        rp.z += a * xr[r].z; rp.w += a * xr[r].w;
    }
    // pbuf free since the post-l[h] barrier (steps since only touched larr/sc)
    pbuf[v * WW + 4 * q + 0] = rp.x;
    pbuf[v * WW + 4 * q + 1] = rp.y;
    pbuf[v * WW + 4 * q + 2] = rp.z;
    pbuf[v * WW + 4 * q + 3] = rp.w;
    __syncthreads();

    // ---- row[w] = (sum_v rp(v,w)) / Z   (reuse larr as row[]) ----
    if (t < WW) {
        float rs = 0.f;
#pragma unroll
        for (int vv = 0; vv < 8; ++vv) rs += pbuf[vv * WW + t];
        larr[t] = rs / sc[1];
    }
    __syncthreads();

    // ---- wave0: beta softmax + s = sum beta*row ----
    if (t < 32) {
        const float S = sc[2];
        float rv[5], bl[5];
#pragma unroll
        for (int j = 0; j < 5; ++j) { rv[j] = larr[t + 32 * j]; bl[j] = rv[j] * S; }
        float mb = bl[0];
#pragma unroll
        for (int j = 1; j < 5; ++j) mb = fmaxf(mb, bl[j]);
#pragma unroll
        for (int off = 16; off >= 1; off >>= 1)
            mb = fmaxf(mb, __shfl_down(mb, off, 32));
        mb = __shfl(mb, 0, 32);
        float zb = 0.f, sd = 0.f;
#pragma unroll
        for (int j = 0; j < 5; ++j) {
            float e = __expf(bl[j] - mb);
            zb += e; sd += e * rv[j];
        }
#pragma unroll
        for (int off = 16; off >= 1; off >>= 1) {
            zb += __shfl_down(zb, off, 32);
            sd += __shfl_down(sd, off, 32);
        }
        if (t == 0) sc[3] = sd / zb;
    }
    __syncthreads();

    // ---- broadcast store (coalesced, nontemporal: out never re-read;
    //      avoids allocating 210 MB of store lines -> less poison eviction) ----
    const float sv = sc[3];
    const f32x4 o = { sv, sv, sv, sv };
#pragma unroll
    for (int r = 0; r < RPT; ++r)
        __builtin_nontemporal_store(
            o, (f32x4*)(op + (size_t)(v * RPT + r) * WW + 4 * q));
}

extern "C" void kernel_launch(void* const* d_in, const int* in_sizes, int n_in,
                              void* d_out, int out_size, void* d_ws, size_t ws_size,
                              hipStream_t stream) {
    const float* x     = (const float*)d_in[0];
    const float* fcw_w = (const float*)d_in[1];
    // d_in[2] = fcw_b: softmax-shift-invariant, unused
    const float* fch_w = (const float*)d_in[3];
    // d_in[4] = fch_b: softmax-shift-invariant, unused
    float* out = (float*)d_out;

    const int nplanes = 8 * 256;  // B*C
    sa1_kernel<<<nplanes, BLOCK, 0, stream>>>(x, fcw_w, fch_w, out);
}

// Round 5
// 345.578 us; speedup vs baseline: 1.2351x; 1.0050x over previous
//
#include <hip/hip_runtime.h>

// Problem: B=8, C=256, H=W=160. n = B*C = 2048 planes.
// Per plane: l[h]=x[h,:]·fcw_w ; alpha=softmax_h(l) ; row[w]=sum_h alpha[h]x[h,w]
//            beta=softmax_w(row*sum(fch_w)) ; s=sum_w beta[w]row[w] ; out[:,:]=s
// Biases are softmax-shift-invariant -> ignored.
//
// v5: SPLIT into two pure-streaming kernels.
//   sa1_reduce: v4's math, ends by writing the scalar s[n] to workspace.
//               Pure read-stream (212 MB) -> runs at read ceiling.
//   sa1_bcast:  memset-shaped broadcast of s[n] over the plane (210 MB nt
//               writes) -> runs at fill ceiling (fills measure 6.5 TB/s).
// Rationale: fused v4 ran ~89us vs ~65us traffic floor because the
// barrier-separated compute mid-section sat between the load burst and the
// store burst (3 blocks/CU can't fully cover it). Reads and writes share
// HBM BW, so serializing the two phases costs nothing; each now runs with
// no compute in its critical path. Same-stream ordering handles the s
// dependency (runtime flushes L2 between dependent dispatches).

#define HH 160
#define WW 160
#define NPLANE (HH * WW)
#define BLOCK 320
#define RPT 20   // rows per v-group
#define QN 40    // float4 columns per row
#define PSTR 41  // pad 41: bank = (9h+q)%32 -> conflict-free gather by h

typedef float f32x4 __attribute__((ext_vector_type(4)));

__global__ void __launch_bounds__(BLOCK) sa1_reduce(
    const float* __restrict__ x,
    const float* __restrict__ fcw_w,
    const float* __restrict__ fch_w,
    float* __restrict__ s_out)
{
    const int n = blockIdx.x;
    const int t = threadIdx.x;
    const int q = t % QN;
    const int v = t / QN;

    __shared__ float pbuf[HH * PSTR];  // logit partials, later row partials [8][160]
    __shared__ float larr[HH];         // logits -> a[h]=exp(l-m) -> row[]
    __shared__ float sc[4];            // m, Z, S(=sum fch_w)

    const float* xp = x + (size_t)n * NPLANE;

    const float4 ww = *(const float4*)(fcw_w + 4 * q);

    // ---- load my 20 float4 (coalesced, nontemporal: x read exactly once) ----
    f32x4 xr[RPT];
#pragma unroll
    for (int r = 0; r < RPT; ++r)
        xr[r] = __builtin_nontemporal_load(
            (const f32x4*)(xp + (size_t)(v * RPT + r) * WW + 4 * q));

    // ---- logit partials: p(h,q) = x4 . ww4 ----
#pragma unroll
    for (int r = 0; r < RPT; ++r) {
        float p = xr[r].x * ww.x + xr[r].y * ww.y + xr[r].z * ww.z + xr[r].w * ww.w;
        pbuf[(v * RPT + r) * PSTR + q] = p;
    }
    __syncthreads();

    // ---- l[h] = sum_q p(h,q)  (threads 0..159, banks (9t+q)%32: 2-way, free) ----
    if (t < HH) {
        const float* pr = pbuf + t * PSTR;
        float s0 = 0.f, s1 = 0.f, s2 = 0.f, s3 = 0.f;
#pragma unroll
        for (int qq = 0; qq < QN; qq += 4) {
            s0 += pr[qq]; s1 += pr[qq + 1]; s2 += pr[qq + 2]; s3 += pr[qq + 3];
        }
        larr[t] = (s0 + s1) + (s2 + s3);
    }
    __syncthreads();

    // ---- wave0: softmax stats m, Z over l[0..159]; wave1: S = sum(fch_w) ----
    if (t < 32) {
        float lv[5];
#pragma unroll
        for (int j = 0; j < 5; ++j) lv[j] = larr[t + 32 * j];
        float m = lv[0];
#pragma unroll
        for (int j = 1; j < 5; ++j) m = fmaxf(m, lv[j]);
#pragma unroll
        for (int off = 16; off >= 1; off >>= 1)
            m = fmaxf(m, __shfl_down(m, off, 32));
        m = __shfl(m, 0, 32);
        float z = 0.f;
#pragma unroll
        for (int j = 0; j < 5; ++j) z += __expf(lv[j] - m);
#pragma unroll
        for (int off = 16; off >= 1; off >>= 1)
            z += __shfl_down(z, off, 32);
        if (t == 0) { sc[0] = m; sc[1] = z; }
    } else if (t >= 64 && t < 96) {
        const int u = t - 64;
        float s = 0.f;
#pragma unroll
        for (int j = 0; j < 5; ++j) s += fch_w[u + 32 * j];
#pragma unroll
        for (int off = 16; off >= 1; off >>= 1)
            s += __shfl_down(s, off, 32);
        if (u == 0) sc[2] = s;
    }
    __syncthreads();

    // ---- a[h] = exp(l[h]-m), once per block ----
    if (t < HH) larr[t] = __expf(larr[t] - sc[0]);
    __syncthreads();

    // ---- row partials: rp = sum_r a[h] * x4  (x4 still in registers) ----
    float4 rp = make_float4(0.f, 0.f, 0.f, 0.f);
#pragma unroll
    for (int r = 0; r < RPT; ++r) {
        const float a = larr[v * RPT + r];  // LDS broadcast read
        rp.x += a * xr[r].x; rp.y += a * xr[r].y;
        rp.z += a * xr[r].z; rp.w += a * xr[r].w;
    }
    // pbuf free since the post-l[h] barrier (steps since only touched larr/sc)
    pbuf[v * WW + 4 * q + 0] = rp.x;
    pbuf[v * WW + 4 * q + 1] = rp.y;
    pbuf[v * WW + 4 * q + 2] = rp.z;
    pbuf[v * WW + 4 * q + 3] = rp.w;
    __syncthreads();

    // ---- row[w] = (sum_v rp(v,w)) / Z   (reuse larr as row[]) ----
    if (t < WW) {
        float rs = 0.f;
#pragma unroll
        for (int vv = 0; vv < 8; ++vv) rs += pbuf[vv * WW + t];
        larr[t] = rs / sc[1];
    }
    __syncthreads();

    // ---- wave0: beta softmax + s = sum beta*row ; write scalar result ----
    if (t < 32) {
        const float S = sc[2];
        float rv[5], bl[5];
#pragma unroll
        for (int j = 0; j < 5; ++j) { rv[j] = larr[t + 32 * j]; bl[j] = rv[j] * S; }
        float mb = bl[0];
#pragma unroll
        for (int j = 1; j < 5; ++j) mb = fmaxf(mb, bl[j]);
#pragma unroll
        for (int off = 16; off >= 1; off >>= 1)
            mb = fmaxf(mb, __shfl_down(mb, off, 32));
        mb = __shfl(mb, 0, 32);
        float zb = 0.f, sd = 0.f;
#pragma unroll
        for (int j = 0; j < 5; ++j) {
            float e = __expf(bl[j] - mb);
            zb += e; sd += e * rv[j];
        }
#pragma unroll
        for (int off = 16; off >= 1; off >>= 1) {
            zb += __shfl_down(zb, off, 32);
            sd += __shfl_down(sd, off, 32);
        }
        if (t == 0) s_out[n] = sd / zb;
    }
}

// ---- broadcast kernel: out[n,:,:] = s[n]; memset-shaped, nt stores ----
#define BBLK 256
#define BIT (NPLANE / 4 / BBLK)  // 25 float4 iterations per thread

__global__ void __launch_bounds__(BBLK) sa1_bcast(
    const float* __restrict__ s, float* __restrict__ out)
{
    const int n = blockIdx.x;
    const float sv = s[n];  // uniform per block -> scalar load
    const f32x4 o = { sv, sv, sv, sv };
    float* op = out + (size_t)n * NPLANE;
#pragma unroll
    for (int i = 0; i < BIT; ++i)
        __builtin_nontemporal_store(
            o, (f32x4*)(op + 4 * (size_t)(i * BBLK + threadIdx.x)));
}

extern "C" void kernel_launch(void* const* d_in, const int* in_sizes, int n_in,
                              void* d_out, int out_size, void* d_ws, size_t ws_size,
                              hipStream_t stream) {
    const float* x     = (const float*)d_in[0];
    const float* fcw_w = (const float*)d_in[1];
    // d_in[2] = fcw_b: softmax-shift-invariant, unused
    const float* fch_w = (const float*)d_in[3];
    // d_in[4] = fch_b: softmax-shift-invariant, unused
    float* out = (float*)d_out;
    float* svec = (float*)d_ws;  // 2048 floats = 8 KB scratch

    const int nplanes = 8 * 256;  // B*C
    sa1_reduce<<<nplanes, BLOCK, 0, stream>>>(x, fcw_w, fch_w, svec);
    sa1_bcast<<<nplanes, BBLK, 0, stream>>>(svec, out);
}

// Round 6
// 345.431 us; speedup vs baseline: 1.2356x; 1.0004x over previous
//
#include <hip/hip_runtime.h>

// Problem: B=8, C=256, H=W=160. n = B*C = 2048 planes.
// Per plane: l[h]=x[h,:]·fcw_w ; alpha=softmax_h(l) ; row[w]=sum_h alpha[h]x[h,w]
//            beta=softmax_w(row*sum(fch_w)) ; s=sum_w beta[w]row[w] ; out[:,:]=s
// Biases are softmax-shift-invariant -> ignored.
//
// v6 = v5 split (reduce -> s[n] scratch; memset-shaped bcast) with a
// SHORTENED reduce tail. v5 evidence: reduce ~52us vs 33us read floor;
// 3 blocks/CU convoy -> synchronized barrier tails expose ~19us of idle
// memory pipe. Tail cuts:
//   - 6 barriers -> 4 (inline exp into weighted pass; merge row-reduce
//     into the final wave0 phase)
//   - l[h] reduction uses all 320 threads (two half-sums A/B)
//   - /Z via one reciprocal at the end
// Everything else proven best kept: x read once into registers (nt loads),
// nt stores in bcast (poison-writeback fix, v4), split kernels.

#define HH 160
#define WW 160
#define NPLANE (HH * WW)
#define BLOCK 320
#define RPT 20   // rows per v-group
#define QN 40    // float4 columns per row
#define PSTR 41  // pad 41: bank = (9h+q)%32 -> conflict-free gather by h

typedef float f32x4 __attribute__((ext_vector_type(4)));

__global__ void __launch_bounds__(BLOCK) sa1_reduce(
    const float* __restrict__ x,
    const float* __restrict__ fcw_w,
    const float* __restrict__ fch_w,
    float* __restrict__ s_out)
{
    const int n = blockIdx.x;
    const int t = threadIdx.x;
    const int q = t % QN;
    const int v = t / QN;

    __shared__ float pbuf[HH * PSTR];  // logit partials; later row partials [8][160]
    __shared__ float larrA[HH];        // l[h] half-sum (q 0..19)
    __shared__ float larrB[HH];        // l[h] half-sum (q 20..39)
    __shared__ float sc[4];            // m, Z, S(=sum fch_w)

    const float* xp = x + (size_t)n * NPLANE;

    const float4 ww = *(const float4*)(fcw_w + 4 * q);

    // ---- P1: load my 20 float4 (coalesced nt) + dot partials into pbuf ----
    f32x4 xr[RPT];
#pragma unroll
    for (int r = 0; r < RPT; ++r)
        xr[r] = __builtin_nontemporal_load(
            (const f32x4*)(xp + (size_t)(v * RPT + r) * WW + 4 * q));
#pragma unroll
    for (int r = 0; r < RPT; ++r) {
        float p = xr[r].x * ww.x + xr[r].y * ww.y + xr[r].z * ww.z + xr[r].w * ww.w;
        pbuf[(v * RPT + r) * PSTR + q] = p;
    }
    __syncthreads();  // B1

    // ---- P2: l[h] half-sums, ALL 320 threads (banks (9h+qq)%32: ~2-way) ----
    {
        const int h = (t < HH) ? t : (t - HH);
        const int qb = (t < HH) ? 0 : (QN / 2);
        const float* pr = pbuf + h * PSTR + qb;
        float s0 = 0.f, s1 = 0.f, s2 = 0.f, s3 = 0.f;
#pragma unroll
        for (int qq = 0; qq < QN / 2; qq += 4) {
            s0 += pr[qq]; s1 += pr[qq + 1]; s2 += pr[qq + 2]; s3 += pr[qq + 3];
        }
        float hs = (s0 + s1) + (s2 + s3);
        if (t < HH) larrA[h] = hs; else larrB[h] = hs;
    }
    __syncthreads();  // B2

    // ---- P3: wave0 = softmax stats m, Z over l[0..159]; wave1 = S ----
    if (t < 32) {
        float lv[5];
#pragma unroll
        for (int j = 0; j < 5; ++j) lv[j] = larrA[t + 32 * j] + larrB[t + 32 * j];
        float m = lv[0];
#pragma unroll
        for (int j = 1; j < 5; ++j) m = fmaxf(m, lv[j]);
#pragma unroll
        for (int off = 16; off >= 1; off >>= 1)
            m = fmaxf(m, __shfl_down(m, off, 32));
        m = __shfl(m, 0, 32);
        float z = 0.f;
#pragma unroll
        for (int j = 0; j < 5; ++j) z += __expf(lv[j] - m);
#pragma unroll
        for (int off = 16; off >= 1; off >>= 1)
            z += __shfl_down(z, off, 32);
        if (t == 0) { sc[0] = m; sc[1] = z; }
    } else if (t >= 64 && t < 96) {
        const int u = t - 64;
        float s = 0.f;
#pragma unroll
        for (int j = 0; j < 5; ++j) s += fch_w[u + 32 * j];
#pragma unroll
        for (int off = 16; off >= 1; off >>= 1)
            s += __shfl_down(s, off, 32);
        if (u == 0) sc[2] = s;
    }
    __syncthreads();  // B3

    // ---- P5: weighted row partials, exp INLINE (x4 still in registers) ----
    const float m = sc[0];
    float4 rp = make_float4(0.f, 0.f, 0.f, 0.f);
#pragma unroll
    for (int r = 0; r < RPT; ++r) {
        const int h = v * RPT + r;
        const float a = __expf((larrA[h] + larrB[h]) - m);  // LDS broadcasts
        rp.x += a * xr[r].x; rp.y += a * xr[r].y;
        rp.z += a * xr[r].z; rp.w += a * xr[r].w;
    }
    // pbuf dead since B2 (P3 only read larrA/B); write row partials [8][160]
    *(float4*)(pbuf + v * WW + 4 * q) = rp;
    __syncthreads();  // B4

    // ---- P7: wave0 merged row-reduce + beta softmax + s ----
    if (t < 32) {
        const float S = sc[2];
        const float rcpZ = 1.0f / sc[1];
        float rv[5], bl[5];
#pragma unroll
        for (int j = 0; j < 5; ++j) {
            const int w = t + 32 * j;
            float rs = 0.f;
#pragma unroll
            for (int vv = 0; vv < 8; ++vv) rs += pbuf[vv * WW + w];  // bank=w%32: clean
            rv[j] = rs * rcpZ;
            bl[j] = rv[j] * S;
        }
        float mb = bl[0];
#pragma unroll
        for (int j = 1; j < 5; ++j) mb = fmaxf(mb, bl[j]);
#pragma unroll
        for (int off = 16; off >= 1; off >>= 1)
            mb = fmaxf(mb, __shfl_down(mb, off, 32));
        mb = __shfl(mb, 0, 32);
        float zb = 0.f, sd = 0.f;
#pragma unroll
        for (int j = 0; j < 5; ++j) {
            float e = __expf(bl[j] - mb);
            zb += e; sd += e * rv[j];
        }
#pragma unroll
        for (int off = 16; off >= 1; off >>= 1) {
            zb += __shfl_down(zb, off, 32);
            sd += __shfl_down(sd, off, 32);
        }
        if (t == 0) s_out[n] = sd / zb;
    }
}

// ---- broadcast kernel: out[n,:,:] = s[n]; memset-shaped, nt stores ----
#define BBLK 256
#define BIT (NPLANE / 4 / BBLK)  // 25 float4 iterations per thread

__global__ void __launch_bounds__(BBLK) sa1_bcast(
    const float* __restrict__ s, float* __restrict__ out)
{
    const int n = blockIdx.x;
    const float sv = s[n];  // uniform per block -> scalar load
    const f32x4 o = { sv, sv, sv, sv };
    float* op = out + (size_t)n * NPLANE;
#pragma unroll
    for (int i = 0; i < BIT; ++i)
        __builtin_nontemporal_store(
            o, (f32x4*)(op + 4 * (size_t)(i * BBLK + threadIdx.x)));
}

extern "C" void kernel_launch(void* const* d_in, const int* in_sizes, int n_in,
                              void* d_out, int out_size, void* d_ws, size_t ws_size,
                              hipStream_t stream) {
    const float* x     = (const float*)d_in[0];
    const float* fcw_w = (const float*)d_in[1];
    // d_in[2] = fcw_b: softmax-shift-invariant, unused
    const float* fch_w = (const float*)d_in[3];
    // d_in[4] = fch_b: softmax-shift-invariant, unused
    float* out = (float*)d_out;
    float* svec = (float*)d_ws;  // 2048 floats = 8 KB scratch

    const int nplanes = 8 * 256;  // B*C
    sa1_reduce<<<nplanes, BLOCK, 0, stream>>>(x, fcw_w, fch_w, svec);
    sa1_bcast<<<nplanes, BBLK, 0, stream>>>(svec, out);
}

// Round 7
// 345.243 us; speedup vs baseline: 1.2363x; 1.0005x over previous
//
#include <hip/hip_runtime.h>

// Problem: B=8, C=256, H=W=160. n = B*C = 2048 planes.
// Per plane: l[h]=x[h,:]·fcw_w ; alpha=softmax_h(l) ; row[w]=sum_h alpha[h]x[h,w]
//            beta=softmax_w(row*sum(fch_w)) ; s=sum_w beta[w]row[w] ; out[:,:]=s
// Biases are softmax-shift-invariant -> ignored.
//
// v7 = v6 + __launch_bounds__(320, 4) on sa1_reduce.
// Evidence trail: v5 (split) and v6 (short tail) both neutral vs v4 ->
// reduce's ~52us (4 TB/s for 212 MB) is LOAD-PHASE-bound, not tail-bound.
// The one unmeasured resource: reduce's VGPR count (20 resident float4 =
// 80 VGPR + overhead). If >128, only 2 blocks/CU are resident during the
// load burst (12 waves/CU). Cap at 128 (4 waves/EU) -> 16 waves/CU ->
// 3 blocks/CU -> +50% memory-level parallelism in the burst.
// Single-variable change; if neutral, VGPR was already <=128 and the next
// ablation is nt-loads vs plain loads.

#define HH 160
#define WW 160
#define NPLANE (HH * WW)
#define BLOCK 320
#define RPT 20   // rows per v-group
#define QN 40    // float4 columns per row
#define PSTR 41  // pad 41: bank = (9h+q)%32 -> conflict-free gather by h

typedef float f32x4 __attribute__((ext_vector_type(4)));

__global__ void __launch_bounds__(BLOCK, 4) sa1_reduce(
    const float* __restrict__ x,
    const float* __restrict__ fcw_w,
    const float* __restrict__ fch_w,
    float* __restrict__ s_out)
{
    const int n = blockIdx.x;
    const int t = threadIdx.x;
    const int q = t % QN;
    const int v = t / QN;

    __shared__ float pbuf[HH * PSTR];  // logit partials; later row partials [8][160]
    __shared__ float larrA[HH];        // l[h] half-sum (q 0..19)
    __shared__ float larrB[HH];        // l[h] half-sum (q 20..39)
    __shared__ float sc[4];            // m, Z, S(=sum fch_w)

    const float* xp = x + (size_t)n * NPLANE;

    const float4 ww = *(const float4*)(fcw_w + 4 * q);

    // ---- P1: load my 20 float4 (coalesced nt) + dot partials into pbuf ----
    f32x4 xr[RPT];
#pragma unroll
    for (int r = 0; r < RPT; ++r)
        xr[r] = __builtin_nontemporal_load(
            (const f32x4*)(xp + (size_t)(v * RPT + r) * WW + 4 * q));
#pragma unroll
    for (int r = 0; r < RPT; ++r) {
        float p = xr[r].x * ww.x + xr[r].y * ww.y + xr[r].z * ww.z + xr[r].w * ww.w;
        pbuf[(v * RPT + r) * PSTR + q] = p;
    }
    __syncthreads();  // B1

    // ---- P2: l[h] half-sums, ALL 320 threads (banks (9h+qq)%32: ~2-way) ----
    {
        const int h = (t < HH) ? t : (t - HH);
        const int qb = (t < HH) ? 0 : (QN / 2);
        const float* pr = pbuf + h * PSTR + qb;
        float s0 = 0.f, s1 = 0.f, s2 = 0.f, s3 = 0.f;
#pragma unroll
        for (int qq = 0; qq < QN / 2; qq += 4) {
            s0 += pr[qq]; s1 += pr[qq + 1]; s2 += pr[qq + 2]; s3 += pr[qq + 3];
        }
        float hs = (s0 + s1) + (s2 + s3);
        if (t < HH) larrA[h] = hs; else larrB[h] = hs;
    }
    __syncthreads();  // B2

    // ---- P3: wave0 = softmax stats m, Z over l[0..159]; wave1 = S ----
    if (t < 32) {
        float lv[5];
#pragma unroll
        for (int j = 0; j < 5; ++j) lv[j] = larrA[t + 32 * j] + larrB[t + 32 * j];
        float m = lv[0];
#pragma unroll
        for (int j = 1; j < 5; ++j) m = fmaxf(m, lv[j]);
#pragma unroll
        for (int off = 16; off >= 1; off >>= 1)
            m = fmaxf(m, __shfl_down(m, off, 32));
        m = __shfl(m, 0, 32);
        float z = 0.f;
#pragma unroll
        for (int j = 0; j < 5; ++j) z += __expf(lv[j] - m);
#pragma unroll
        for (int off = 16; off >= 1; off >>= 1)
            z += __shfl_down(z, off, 32);
        if (t == 0) { sc[0] = m; sc[1] = z; }
    } else if (t >= 64 && t < 96) {
        const int u = t - 64;
        float s = 0.f;
#pragma unroll
        for (int j = 0; j < 5; ++j) s += fch_w[u + 32 * j];
#pragma unroll
        for (int off = 16; off >= 1; off >>= 1)
            s += __shfl_down(s, off, 32);
        if (u == 0) sc[2] = s;
    }
    __syncthreads();  // B3

    // ---- P5: weighted row partials, exp INLINE (x4 still in registers) ----
    const float m = sc[0];
    float4 rp = make_float4(0.f, 0.f, 0.f, 0.f);
#pragma unroll
    for (int r = 0; r < RPT; ++r) {
        const int h = v * RPT + r;
        const float a = __expf((larrA[h] + larrB[h]) - m);  // LDS broadcasts
        rp.x += a * xr[r].x; rp.y += a * xr[r].y;
        rp.z += a * xr[r].z; rp.w += a * xr[r].w;
    }
    // pbuf dead since B2 (P3 only read larrA/B); write row partials [8][160]
    *(float4*)(pbuf + v * WW + 4 * q) = rp;
    __syncthreads();  // B4

    // ---- P7: wave0 merged row-reduce + beta softmax + s ----
    if (t < 32) {
        const float S = sc[2];
        const float rcpZ = 1.0f / sc[1];
        float rv[5], bl[5];
#pragma unroll
        for (int j = 0; j < 5; ++j) {
            const int w = t + 32 * j;
            float rs = 0.f;
#pragma unroll
            for (int vv = 0; vv < 8; ++vv) rs += pbuf[vv * WW + w];  // bank=w%32: clean
            rv[j] = rs * rcpZ;
            bl[j] = rv[j] * S;
        }
        float mb = bl[0];
#pragma unroll
        for (int j = 1; j < 5; ++j) mb = fmaxf(mb, bl[j]);
#pragma unroll
        for (int off = 16; off >= 1; off >>= 1)
            mb = fmaxf(mb, __shfl_down(mb, off, 32));
        mb = __shfl(mb, 0, 32);
        float zb = 0.f, sd = 0.f;
#pragma unroll
        for (int j = 0; j < 5; ++j) {
            float e = __expf(bl[j] - mb);
            zb += e; sd += e * rv[j];
        }
#pragma unroll
        for (int off = 16; off >= 1; off >>= 1) {
            zb += __shfl_down(zb, off, 32);
            sd += __shfl_down(sd, off, 32);
        }
        if (t == 0) s_out[n] = sd / zb;
    }
}

// ---- broadcast kernel: out[n,:,:] = s[n]; memset-shaped, nt stores ----
#define BBLK 256
#define BIT (NPLANE / 4 / BBLK)  // 25 float4 iterations per thread

__global__ void __launch_bounds__(BBLK) sa1_bcast(
    const float* __restrict__ s, float* __restrict__ out)
{
    const int n = blockIdx.x;
    const float sv = s[n];  // uniform per block -> scalar load
    const f32x4 o = { sv, sv, sv, sv };
    float* op = out + (size_t)n * NPLANE;
#pragma unroll
    for (int i = 0; i < BIT; ++i)
        __builtin_nontemporal_store(
            o, (f32x4*)(op + 4 * (size_t)(i * BBLK + threadIdx.x)));
}

extern "C" void kernel_launch(void* const* d_in, const int* in_sizes, int n_in,
                              void* d_out, int out_size, void* d_ws, size_t ws_size,
                              hipStream_t stream) {
    const float* x     = (const float*)d_in[0];
    const float* fcw_w = (const float*)d_in[1];
    // d_in[2] = fcw_b: softmax-shift-invariant, unused
    const float* fch_w = (const float*)d_in[3];
    // d_in[4] = fch_b: softmax-shift-invariant, unused
    float* out = (float*)d_out;
    float* svec = (float*)d_ws;  // 2048 floats = 8 KB scratch

    const int nplanes = 8 * 256;  // B*C
    sa1_reduce<<<nplanes, BLOCK, 0, stream>>>(x, fcw_w, fch_w, svec);
    sa1_bcast<<<nplanes, BBLK, 0, stream>>>(svec, out);
}

// Round 8
// 341.216 us; speedup vs baseline: 1.2509x; 1.0118x over previous
//
#include <hip/hip_runtime.h>

// Problem: B=8, C=256, H=W=160. n = B*C = 2048 planes.
// Per plane: l[h]=x[h,:]·fcw_w ; alpha=softmax_h(l) ; row[w]=sum_h alpha[h]x[h,w]
//            beta=softmax_w(row*sum(fch_w)) ; s=sum_w beta[w]row[w] ; out[:,:]=s
// Biases are softmax-shift-invariant -> ignored.
//
// v8: SPLIT-SOFTMAX, 2 blocks per plane (4096 blocks x 80 rows).
// Evidence: v5/v6/v7 all neutral; reduce family stuck at ~4 TB/s while
// memset-shaped fills hit 6.5 TB/s at 10% occupancy. Diagnosis: lockstep
// convoy -- 3 resident blocks/CU burst-load then tail together behind
// barriers; pipe idles during synchronized tails; residency capped by
// 80 VGPRs of x-in-registers per full plane. Halving the plane per block:
// 40 VGPR x-data -> ~70 total -> 28 waves/CU -> 5 blocks/CU, 16
// generations/CU -> smoother interleave. Exact flash-style merge:
// block writes (m_g, Z_g, rowacc_g[160]) to ws; bcast kernel merges
// m=max, f=e^{m_g-m}, row=(f0 R0+f1 R1)/(f0 Z0+f1 Z1) then beta/s/store.
// Fallback to v7 single-block path if ws_size < 2.7 MB.

#define HH 160
#define WW 160
#define NPLANE (HH * WW)
#define BLOCK 320
#define QN 40     // float4 columns per row
#define PSTR 41   // pad: conflict-light LDS partial gather

// -- split kernel geometry --
#define HALF 80   // rows per partial block
#define RPTH 10   // rows per v-group (HALF / 8)
#define WSSTR 164 // floats per ws record: rowacc[160], m, Z, pad2

typedef float f32x4 __attribute__((ext_vector_type(4)));

// ================= v8 partial-reduce: one half-plane per block ============
__global__ void __launch_bounds__(BLOCK, 7) sa1_part(
    const float* __restrict__ x,
    const float* __restrict__ fcw_w,
    float* __restrict__ ws)
{
    const int bid = blockIdx.x;
    const int n = bid >> 1;
    const int g = bid & 1;
    const int t = threadIdx.x;
    const int q = t % QN;
    const int v = t / QN;

    __shared__ float pbuf[HALF * PSTR];  // dot partials; later row partials [8][160]
    __shared__ float larr[HALF];         // l[h] for my 80 rows
    __shared__ float sc[2];              // m_part, Z_part

    const float* xp = x + (size_t)n * NPLANE + (size_t)g * HALF * WW;

    const float4 ww = *(const float4*)(fcw_w + 4 * q);

    // ---- P1: load my 10 float4 (coalesced nt) + dot partials ----
    f32x4 xr[RPTH];
#pragma unroll
    for (int r = 0; r < RPTH; ++r)
        xr[r] = __builtin_nontemporal_load(
            (const f32x4*)(xp + (size_t)(v * RPTH + r) * WW + 4 * q));
#pragma unroll
    for (int r = 0; r < RPTH; ++r) {
        float p = xr[r].x * ww.x + xr[r].y * ww.y + xr[r].z * ww.z + xr[r].w * ww.w;
        pbuf[(v * RPTH + r) * PSTR + q] = p;
    }
    __syncthreads();  // B1

    // ---- P2: l[h], 4 threads per row (80 rows x 4 segs of 10) + 4-lane shfl ----
    {
        const int row = t >> 2;          // [0,80)
        const int seg = t & 3;           // [0,4)
        const float* pr = pbuf + row * PSTR + seg * 10;
        float s0 = 0.f, s1 = 0.f;
#pragma unroll
        for (int i = 0; i < 10; i += 2) { s0 += pr[i]; s1 += pr[i + 1]; }
        float hs = s0 + s1;
        hs += __shfl_xor(hs, 1, 64);
        hs += __shfl_xor(hs, 2, 64);
        if (seg == 0) larr[row] = hs;
    }
    __syncthreads();  // B2

    // ---- P3: wave0 computes m_part, Z_part over 80 logits ----
    if (t < 32) {
        const float l0 = larr[t];
        const float l1 = larr[t + 32];
        const float l2 = (t < 16) ? larr[t + 64] : -3.0e38f;
        float m = fmaxf(l0, fmaxf(l1, l2));
#pragma unroll
        for (int off = 16; off >= 1; off >>= 1)
            m = fmaxf(m, __shfl_down(m, off, 32));
        m = __shfl(m, 0, 32);
        float z = __expf(l0 - m) + __expf(l1 - m) + __expf(l2 - m);  // l2 path underflows to 0
#pragma unroll
        for (int off = 16; off >= 1; off >>= 1)
            z += __shfl_down(z, off, 32);
        if (t == 0) { sc[0] = m; sc[1] = z; }
    }
    __syncthreads();  // B3

    // ---- P4: weighted row partials, exp inline (x still in registers) ----
    const float m = sc[0];
    float4 rp = make_float4(0.f, 0.f, 0.f, 0.f);
#pragma unroll
    for (int r = 0; r < RPTH; ++r) {
        const float a = __expf(larr[v * RPTH + r] - m);  // LDS broadcast
        rp.x += a * xr[r].x; rp.y += a * xr[r].y;
        rp.z += a * xr[r].z; rp.w += a * xr[r].w;
    }
    // pbuf dead since B2; write row partials [8][160]
    *(float4*)(pbuf + v * WW + 4 * q) = rp;
    __syncthreads();  // B4

    // ---- P5: reduce over v, emit ws record {rowacc[160], m, Z} ----
    float* wsr = ws + (size_t)bid * WSSTR;
    if (t < WW) {
        float rs = 0.f;
#pragma unroll
        for (int vv = 0; vv < 8; ++vv) rs += pbuf[vv * WW + t];  // bank=t%32: clean
        wsr[t] = rs;                     // NOT normalized; merge handles Z
    }
    if (t == 0) { wsr[160] = sc[0]; wsr[161] = sc[1]; }
}

// ====== v8 merge + broadcast: wave0 merges 2 partials -> s; all store ======
#define BBLK 256
#define BIT (NPLANE / 4 / BBLK)  // 25 float4 iterations per thread

__global__ void __launch_bounds__(BBLK) sa1_bcast_merge(
    const float* __restrict__ ws,
    const float* __restrict__ fch_w,
    float* __restrict__ out)
{
    const int n = blockIdx.x;
    const int t = threadIdx.x;
    __shared__ float sc[2];  // S, s

    float rv[5];
    if (t < 32) {
        const float* r0 = ws + (size_t)(2 * n) * WSSTR;
        const float* r1 = ws + (size_t)(2 * n + 1) * WSSTR;
        const float m0 = r0[160], z0 = r0[161];
        const float m1 = r1[160], z1 = r1[161];
        const float mm = fmaxf(m0, m1);
        const float f0 = __expf(m0 - mm);
        const float f1 = __expf(m1 - mm);
        const float rcpZ = 1.0f / (f0 * z0 + f1 * z1);
#pragma unroll
        for (int j = 0; j < 5; ++j) {
            const int w = t + 32 * j;
            rv[j] = (f0 * r0[w] + f1 * r1[w]) * rcpZ;  // row[w]
        }
    } else if (t >= 64 && t < 96) {
        const int u = t - 64;
        float s = 0.f;
#pragma unroll
        for (int j = 0; j < 5; ++j) s += fch_w[u + 32 * j];
#pragma unroll
        for (int off = 16; off >= 1; off >>= 1)
            s += __shfl_down(s, off, 32);
        if (u == 0) sc[0] = s;
    }
    __syncthreads();

    if (t < 32) {
        const float S = sc[0];
        float bl[5];
#pragma unroll
        for (int j = 0; j < 5; ++j) bl[j] = rv[j] * S;
        float mb = bl[0];
#pragma unroll
        for (int j = 1; j < 5; ++j) mb = fmaxf(mb, bl[j]);
#pragma unroll
        for (int off = 16; off >= 1; off >>= 1)
            mb = fmaxf(mb, __shfl_down(mb, off, 32));
        mb = __shfl(mb, 0, 32);
        float zb = 0.f, sd = 0.f;
#pragma unroll
        for (int j = 0; j < 5; ++j) {
            float e = __expf(bl[j] - mb);
            zb += e; sd += e * rv[j];
        }
#pragma unroll
        for (int off = 16; off >= 1; off >>= 1) {
            zb += __shfl_down(zb, off, 32);
            sd += __shfl_down(sd, off, 32);
        }
        if (t == 0) sc[1] = sd / zb;
    }
    __syncthreads();

    const float sv = sc[1];
    const f32x4 o = { sv, sv, sv, sv };
    float* op = out + (size_t)n * NPLANE;
#pragma unroll
    for (int i = 0; i < BIT; ++i)
        __builtin_nontemporal_store(
            o, (f32x4*)(op + 4 * (size_t)(i * BBLK + threadIdx.x)));
}

// ================= fallback (v7 path) if workspace is too small ===========
#define RPT 20

__global__ void __launch_bounds__(BLOCK, 4) sa1_reduce(
    const float* __restrict__ x,
    const float* __restrict__ fcw_w,
    const float* __restrict__ fch_w,
    float* __restrict__ s_out)
{
    const int n = blockIdx.x;
    const int t = threadIdx.x;
    const int q = t % QN;
    const int v = t / QN;

    __shared__ float pbuf[HH * PSTR];
    __shared__ float larrA[HH];
    __shared__ float larrB[HH];
    __shared__ float sc[4];

    const float* xp = x + (size_t)n * NPLANE;
    const float4 ww = *(const float4*)(fcw_w + 4 * q);

    f32x4 xr[RPT];
#pragma unroll
    for (int r = 0; r < RPT; ++r)
        xr[r] = __builtin_nontemporal_load(
            (const f32x4*)(xp + (size_t)(v * RPT + r) * WW + 4 * q));
#pragma unroll
    for (int r = 0; r < RPT; ++r) {
        float p = xr[r].x * ww.x + xr[r].y * ww.y + xr[r].z * ww.z + xr[r].w * ww.w;
        pbuf[(v * RPT + r) * PSTR + q] = p;
    }
    __syncthreads();

    {
        const int h = (t < HH) ? t : (t - HH);
        const int qb = (t < HH) ? 0 : (QN / 2);
        const float* pr = pbuf + h * PSTR + qb;
        float s0 = 0.f, s1 = 0.f, s2 = 0.f, s3 = 0.f;
#pragma unroll
        for (int qq = 0; qq < QN / 2; qq += 4) {
            s0 += pr[qq]; s1 += pr[qq + 1]; s2 += pr[qq + 2]; s3 += pr[qq + 3];
        }
        float hs = (s0 + s1) + (s2 + s3);
        if (t < HH) larrA[h] = hs; else larrB[h] = hs;
    }
    __syncthreads();

    if (t < 32) {
        float lv[5];
#pragma unroll
        for (int j = 0; j < 5; ++j) lv[j] = larrA[t + 32 * j] + larrB[t + 32 * j];
        float m = lv[0];
#pragma unroll
        for (int j = 1; j < 5; ++j) m = fmaxf(m, lv[j]);
#pragma unroll
        for (int off = 16; off >= 1; off >>= 1)
            m = fmaxf(m, __shfl_down(m, off, 32));
        m = __shfl(m, 0, 32);
        float z = 0.f;
#pragma unroll
        for (int j = 0; j < 5; ++j) z += __expf(lv[j] - m);
#pragma unroll
        for (int off = 16; off >= 1; off >>= 1)
            z += __shfl_down(z, off, 32);
        if (t == 0) { sc[0] = m; sc[1] = z; }
    } else if (t >= 64 && t < 96) {
        const int u = t - 64;
        float s = 0.f;
#pragma unroll
        for (int j = 0; j < 5; ++j) s += fch_w[u + 32 * j];
#pragma unroll
        for (int off = 16; off >= 1; off >>= 1)
            s += __shfl_down(s, off, 32);
        if (u == 0) sc[2] = s;
    }
    __syncthreads();

    const float m = sc[0];
    float4 rp = make_float4(0.f, 0.f, 0.f, 0.f);
#pragma unroll
    for (int r = 0; r < RPT; ++r) {
        const int h = v * RPT + r;
        const float a = __expf((larrA[h] + larrB[h]) - m);
        rp.x += a * xr[r].x; rp.y += a * xr[r].y;
        rp.z += a * xr[r].z; rp.w += a * xr[r].w;
    }
    *(float4*)(pbuf + v * WW + 4 * q) = rp;
    __syncthreads();

    if (t < 32) {
        const float S = sc[2];
        const float rcpZ = 1.0f / sc[1];
        float rv[5], bl[5];
#pragma unroll
        for (int j = 0; j < 5; ++j) {
            const int w = t + 32 * j;
            float rs = 0.f;
#pragma unroll
            for (int vv = 0; vv < 8; ++vv) rs += pbuf[vv * WW + w];
            rv[j] = rs * rcpZ;
            bl[j] = rv[j] * S;
        }
        float mb = bl[0];
#pragma unroll
        for (int j = 1; j < 5; ++j) mb = fmaxf(mb, bl[j]);
#pragma unroll
        for (int off = 16; off >= 1; off >>= 1)
            mb = fmaxf(mb, __shfl_down(mb, off, 32));
        mb = __shfl(mb, 0, 32);
        float zb = 0.f, sd = 0.f;
#pragma unroll
        for (int j = 0; j < 5; ++j) {
            float e = __expf(bl[j] - mb);
            zb += e; sd += e * rv[j];
        }
#pragma unroll
        for (int off = 16; off >= 1; off >>= 1) {
            zb += __shfl_down(zb, off, 32);
            sd += __shfl_down(sd, off, 32);
        }
        if (t == 0) s_out[n] = sd / zb;
    }
}

__global__ void __launch_bounds__(BBLK) sa1_bcast(
    const float* __restrict__ s, float* __restrict__ out)
{
    const int n = blockIdx.x;
    const float sv = s[n];
    const f32x4 o = { sv, sv, sv, sv };
    float* op = out + (size_t)n * NPLANE;
#pragma unroll
    for (int i = 0; i < BIT; ++i)
        __builtin_nontemporal_store(
            o, (f32x4*)(op + 4 * (size_t)(i * BBLK + threadIdx.x)));
}

extern "C" void kernel_launch(void* const* d_in, const int* in_sizes, int n_in,
                              void* d_out, int out_size, void* d_ws, size_t ws_size,
                              hipStream_t stream) {
    const float* x     = (const float*)d_in[0];
    const float* fcw_w = (const float*)d_in[1];
    // d_in[2] = fcw_b: softmax-shift-invariant, unused
    const float* fch_w = (const float*)d_in[3];
    // d_in[4] = fch_b: softmax-shift-invariant, unused
    float* out = (float*)d_out;

    const int nplanes = 8 * 256;  // B*C
    const size_t need = (size_t)(2 * nplanes) * WSSTR * sizeof(float);  // 2.7 MB

    if (ws_size >= need) {
        float* wsp = (float*)d_ws;
        sa1_part<<<2 * nplanes, BLOCK, 0, stream>>>(x, fcw_w, wsp);
        sa1_bcast_merge<<<nplanes, BBLK, 0, stream>>>(wsp, fch_w, out);
    } else {
        float* svec = (float*)d_ws;  // 8 KB
        sa1_reduce<<<nplanes, BLOCK, 0, stream>>>(x, fcw_w, fch_w, svec);
        sa1_bcast<<<nplanes, BBLK, 0, stream>>>(svec, out);
    }
}